// Round 1
// baseline (5075.051 us; speedup 1.0000x reference)
//
#include <hip/hip_runtime.h>
#include <math.h>

#define HID 9000
#define EMB 300
#define NSTEPS 20

__device__ __forceinline__ float sigmoidf_(float v) {
    return 1.0f / (1.0f + expf(-v));
}

__device__ __forceinline__ float waveReduceSum(float v) {
#pragma unroll
    for (int off = 32; off > 0; off >>= 1) v += __shfl_down(v, off, 64);
    return v;
}

// ---------------------------------------------------------------------------
// Priming step: h,c = lstm_cell(x, h=0, c=0).
// gates = x @ w_ih.T + b_ih + b_hh   (h=0 -> w_hh contributes exactly 0)
// c = sigmoid(i)*tanh(g); h = sigmoid(o)*tanh(c)
// One block per hidden unit; wave w handles gate row j + w*HID.
// ---------------------------------------------------------------------------
__global__ __launch_bounds__(256) void prime_kernel(
    const float* __restrict__ x, const float* __restrict__ w_ih,
    const float* __restrict__ b_ih, const float* __restrict__ b_hh,
    float* __restrict__ h, float* __restrict__ c)
{
    const int j = blockIdx.x;
    const int wave = threadIdx.x >> 6;
    const int lane = threadIdx.x & 63;
    const int row = j + wave * HID;
    const float4* __restrict__ wr = (const float4*)(w_ih + (size_t)row * EMB);
    const float4* __restrict__ x4 = (const float4*)x;
    float acc = 0.0f;
    for (int k = lane; k < EMB / 4; k += 64) {
        float4 w = wr[k];
        float4 xv = x4[k];
        acc = fmaf(w.x, xv.x, acc);
        acc = fmaf(w.y, xv.y, acc);
        acc = fmaf(w.z, xv.z, acc);
        acc = fmaf(w.w, xv.w, acc);
    }
    acc = waveReduceSum(acc);
    __shared__ float gl[4];
    if (lane == 0) gl[wave] = acc + b_ih[row] + b_hh[row];
    __syncthreads();
    if (threadIdx.x == 0) {
        float gi = gl[0], gg = gl[2], go = gl[3];
        float cn = sigmoidf_(gi) * tanhf(gg);   // c_prev == 0
        float hn = sigmoidf_(go) * tanhf(cn);
        c[j] = cn;
        h[j] = hn;
    }
}

// ---------------------------------------------------------------------------
// out = h @ w_out.T + b_out    (300 outputs, dot length 9000)
// One block per output element.
// ---------------------------------------------------------------------------
__global__ __launch_bounds__(256) void outvec_kernel(
    const float* __restrict__ h, const float* __restrict__ w_out,
    const float* __restrict__ b_out, float* __restrict__ ovec)
{
    const int i = blockIdx.x;
    const float4* __restrict__ wr = (const float4*)(w_out + (size_t)i * HID);
    const float4* __restrict__ h4 = (const float4*)h;
    float acc = 0.0f;
    for (int k = threadIdx.x; k < HID / 4; k += 256) {
        float4 w = wr[k];
        float4 hv = h4[k];
        acc = fmaf(w.x, hv.x, acc);
        acc = fmaf(w.y, hv.y, acc);
        acc = fmaf(w.z, hv.z, acc);
        acc = fmaf(w.w, hv.w, acc);
    }
    acc = waveReduceSum(acc);
    __shared__ float red[4];
    const int wave = threadIdx.x >> 6;
    const int lane = threadIdx.x & 63;
    if (lane == 0) red[wave] = acc;
    __syncthreads();
    if (threadIdx.x == 0)
        ovec[i] = red[0] + red[1] + red[2] + red[3] + b_out[i];
}

// ---------------------------------------------------------------------------
// gates = ovec @ w_ih.T + b_ih + h @ w_hh.T + b_hh, then cell update.
// One block per hidden unit j; wave w computes gate row j + w*HID.
// Dominant kernel: streams 1.296 GB of w_hh per step.
// ---------------------------------------------------------------------------
__global__ __launch_bounds__(256) void gates_kernel(
    const float* __restrict__ h, const float* __restrict__ ovec,
    const float* __restrict__ w_hh, const float* __restrict__ w_ih,
    const float* __restrict__ b_ih, const float* __restrict__ b_hh,
    float* __restrict__ c, float* __restrict__ h_raw)
{
    const int j = blockIdx.x;
    const int wave = threadIdx.x >> 6;
    const int lane = threadIdx.x & 63;
    const int row = j + wave * HID;

    const float4* __restrict__ wr = (const float4*)(w_hh + (size_t)row * HID);
    const float4* __restrict__ h4 = (const float4*)h;
    float acc = 0.0f;
    for (int k = lane; k < HID / 4; k += 64) {
        float4 w = wr[k];
        float4 hv = h4[k];
        acc = fmaf(w.x, hv.x, acc);
        acc = fmaf(w.y, hv.y, acc);
        acc = fmaf(w.z, hv.z, acc);
        acc = fmaf(w.w, hv.w, acc);
    }
    const float4* __restrict__ wir = (const float4*)(w_ih + (size_t)row * EMB);
    const float4* __restrict__ o4 = (const float4*)ovec;
    for (int k = lane; k < EMB / 4; k += 64) {
        float4 w = wir[k];
        float4 ov = o4[k];
        acc = fmaf(w.x, ov.x, acc);
        acc = fmaf(w.y, ov.y, acc);
        acc = fmaf(w.z, ov.z, acc);
        acc = fmaf(w.w, ov.w, acc);
    }
    acc = waveReduceSum(acc);
    __shared__ float gl[4];
    if (lane == 0) gl[wave] = acc + b_ih[row] + b_hh[row];
    __syncthreads();
    if (threadIdx.x == 0) {
        float gi = gl[0], gf = gl[1], gg = gl[2], go = gl[3];
        float cp = c[j];
        float cn = sigmoidf_(gf) * cp + sigmoidf_(gi) * tanhf(gg);
        float hn = sigmoidf_(go) * tanhf(cn);
        c[j] = cn;
        h_raw[j] = hn;
    }
}

// ---------------------------------------------------------------------------
// h = softmax(h_raw); also store output column t: out[k*NSTEPS + t] = h[k].
// Single 1024-thread block (9000 elements, ~9 per thread).
// ---------------------------------------------------------------------------
__global__ __launch_bounds__(1024) void softmax_kernel(
    const float* __restrict__ h_raw, float* __restrict__ h,
    float* __restrict__ outp, int t)
{
    __shared__ float red[16];
    __shared__ float bcast;
    const int tid = threadIdx.x;
    const int wave = tid >> 6;
    const int lane = tid & 63;

    float m = -INFINITY;
    for (int k = tid; k < HID; k += 1024) m = fmaxf(m, h_raw[k]);
#pragma unroll
    for (int off = 32; off > 0; off >>= 1) m = fmaxf(m, __shfl_down(m, off, 64));
    if (lane == 0) red[wave] = m;
    __syncthreads();
    if (tid == 0) {
        float mm = red[0];
        for (int i = 1; i < 16; i++) mm = fmaxf(mm, red[i]);
        bcast = mm;
    }
    __syncthreads();
    const float M = bcast;

    float s = 0.0f;
    for (int k = tid; k < HID; k += 1024) s += expf(h_raw[k] - M);
    s = waveReduceSum(s);
    if (lane == 0) red[wave] = s;      // WAR on red[] is across the sync above
    __syncthreads();
    if (tid == 0) {
        float ss = 0.0f;
        for (int i = 0; i < 16; i++) ss += red[i];
        bcast = ss;
    }
    __syncthreads();
    const float invS = 1.0f / bcast;

    for (int k = tid; k < HID; k += 1024) {
        float v = expf(h_raw[k] - M) * invS;
        h[k] = v;
        outp[(size_t)k * NSTEPS + t] = v;
    }
}

extern "C" void kernel_launch(void* const* d_in, const int* in_sizes, int n_in,
                              void* d_out, int out_size, void* d_ws, size_t ws_size,
                              hipStream_t stream)
{
    const float* x     = (const float*)d_in[0];
    const float* w_ih  = (const float*)d_in[1];
    const float* w_hh  = (const float*)d_in[2];
    const float* b_ih  = (const float*)d_in[3];
    const float* b_hh  = (const float*)d_in[4];
    const float* w_out = (const float*)d_in[5];
    const float* b_out = (const float*)d_in[6];
    float* outp = (float*)d_out;

    float* ws = (float*)d_ws;
    float* h     = ws;            // 9000 floats
    float* c     = ws + 9008;     // 9000 floats (offsets kept 16B-aligned)
    float* ovec  = ws + 18016;    // 300 floats
    float* h_raw = ws + 18336;    // 9000 floats

    prime_kernel<<<HID, 256, 0, stream>>>(x, w_ih, b_ih, b_hh, h, c);
    for (int t = 0; t < NSTEPS; ++t) {
        outvec_kernel<<<EMB, 256, 0, stream>>>(h, w_out, b_out, ovec);
        gates_kernel<<<HID, 256, 0, stream>>>(h, ovec, w_hh, w_ih, b_ih, b_hh, c, h_raw);
        softmax_kernel<<<1, 1024, 0, stream>>>(h_raw, h, outp, t);
    }
}

// Round 2
// 3625.862 us; speedup vs baseline: 1.3997x; 1.3997x over previous
//
#include <hip/hip_runtime.h>
#include <hip/hip_fp16.h>
#include <math.h>

#define HID 9000
#define EMB 300
#define NSTEPS 20
#define HID8 (HID / 8)   // 1125 eight-half chunks per w_hh/w_out row
#define EMB4 (EMB / 4)   // 75 four-half chunks per w_ih row

__device__ __forceinline__ float sigmoidf_(float v) {
    return 1.0f / (1.0f + expf(-v));
}

__device__ __forceinline__ float waveReduceSum(float v) {
#pragma unroll
    for (int off = 32; off > 0; off >>= 1) v += __shfl_down(v, off, 64);
    return v;
}

// ---------------------------------------------------------------------------
// fp32 -> fp16 weight compression, 8 elements/thread/iter (32B in, 16B out).
// ---------------------------------------------------------------------------
__global__ __launch_bounds__(256) void f32_to_f16_kernel(
    const float* __restrict__ src, __half* __restrict__ dst, int n8)
{
    int i = blockIdx.x * blockDim.x + threadIdx.x;
    const int stride = gridDim.x * blockDim.x;
    const float4* __restrict__ s4 = (const float4*)src;
    float4* __restrict__ d4 = (float4*)dst;
    for (; i < n8; i += stride) {
        float4 a = s4[2 * i];
        float4 b = s4[2 * i + 1];
        float4 o;
        ((__half2*)&o)[0] = __floats2half2_rn(a.x, a.y);
        ((__half2*)&o)[1] = __floats2half2_rn(a.z, a.w);
        ((__half2*)&o)[2] = __floats2half2_rn(b.x, b.y);
        ((__half2*)&o)[3] = __floats2half2_rn(b.z, b.w);
        d4[i] = o;
    }
}

// ---------------------------------------------------------------------------
// Priming step (fp16 w_ih): h,c = lstm_cell(x, 0, 0); w_hh term is exactly 0.
// ---------------------------------------------------------------------------
__global__ __launch_bounds__(256) void prime_kernel_h(
    const float* __restrict__ x, const __half* __restrict__ w_ih,
    const float* __restrict__ b_ih, const float* __restrict__ b_hh,
    float* __restrict__ h, float* __restrict__ c)
{
    const int j = blockIdx.x;
    const int wave = threadIdx.x >> 6;
    const int lane = threadIdx.x & 63;
    const int row = j + wave * HID;
    const float2* __restrict__ wr = (const float2*)(w_ih + (size_t)row * EMB);
    const float4* __restrict__ x4 = (const float4*)x;
    float acc = 0.0f;
    for (int k = lane; k < EMB4; k += 64) {
        float2 wv = wr[k];
        const __half2* wh = (const __half2*)&wv;
        float2 w0 = __half22float2(wh[0]);
        float2 w1 = __half22float2(wh[1]);
        float4 xv = x4[k];
        acc = fmaf(w0.x, xv.x, acc);
        acc = fmaf(w0.y, xv.y, acc);
        acc = fmaf(w1.x, xv.z, acc);
        acc = fmaf(w1.y, xv.w, acc);
    }
    acc = waveReduceSum(acc);
    __shared__ float gl[4];
    if (lane == 0) gl[wave] = acc + b_ih[row] + b_hh[row];
    __syncthreads();
    if (threadIdx.x == 0) {
        float gi = gl[0], gg = gl[2], go = gl[3];
        float cn = sigmoidf_(gi) * tanhf(gg);
        float hn = sigmoidf_(go) * tanhf(cn);
        c[j] = cn;
        h[j] = hn;
    }
}

// ---------------------------------------------------------------------------
// out = h @ w_out.T + b_out  (fp16 w_out; rows are 18000B -> 16B aligned)
// ---------------------------------------------------------------------------
__global__ __launch_bounds__(256) void outvec_kernel_h(
    const float* __restrict__ h, const __half* __restrict__ w_out,
    const float* __restrict__ b_out, float* __restrict__ ovec)
{
    const int i = blockIdx.x;
    const float4* __restrict__ wr = (const float4*)(w_out + (size_t)i * HID);
    const float4* __restrict__ h4 = (const float4*)h;
    float acc = 0.0f;
    for (int k = threadIdx.x; k < HID8; k += 256) {
        float4 wv = wr[k];
        const __half2* wh = (const __half2*)&wv;
        float4 ha = h4[2 * k];
        float4 hb = h4[2 * k + 1];
        float2 w0 = __half22float2(wh[0]);
        float2 w1 = __half22float2(wh[1]);
        float2 w2 = __half22float2(wh[2]);
        float2 w3 = __half22float2(wh[3]);
        acc = fmaf(w0.x, ha.x, acc);
        acc = fmaf(w0.y, ha.y, acc);
        acc = fmaf(w1.x, ha.z, acc);
        acc = fmaf(w1.y, ha.w, acc);
        acc = fmaf(w2.x, hb.x, acc);
        acc = fmaf(w2.y, hb.y, acc);
        acc = fmaf(w3.x, hb.z, acc);
        acc = fmaf(w3.y, hb.w, acc);
    }
    acc = waveReduceSum(acc);
    __shared__ float red[4];
    const int wave = threadIdx.x >> 6;
    const int lane = threadIdx.x & 63;
    if (lane == 0) red[wave] = acc;
    __syncthreads();
    if (threadIdx.x == 0)
        ovec[i] = red[0] + red[1] + red[2] + red[3] + b_out[i];
}

// ---------------------------------------------------------------------------
// gates = ovec @ w_ih.T + b_ih + h @ w_hh.T + b_hh, then cell update.
// fp16 weights. One block per hidden unit j; wave w owns gate row j + w*HID.
// ---------------------------------------------------------------------------
__global__ __launch_bounds__(256) void gates_kernel_h(
    const float* __restrict__ h, const float* __restrict__ ovec,
    const __half* __restrict__ w_hh, const __half* __restrict__ w_ih,
    const float* __restrict__ b_ih, const float* __restrict__ b_hh,
    float* __restrict__ c, float* __restrict__ h_raw)
{
    const int j = blockIdx.x;
    const int wave = threadIdx.x >> 6;
    const int lane = threadIdx.x & 63;
    const int row = j + wave * HID;

    const float4* __restrict__ wr = (const float4*)(w_hh + (size_t)row * HID);
    const float4* __restrict__ h4 = (const float4*)h;
    float acc = 0.0f;
    for (int k = lane; k < HID8; k += 64) {
        float4 wv = wr[k];
        const __half2* wh = (const __half2*)&wv;
        float4 ha = h4[2 * k];
        float4 hb = h4[2 * k + 1];
        float2 w0 = __half22float2(wh[0]);
        float2 w1 = __half22float2(wh[1]);
        float2 w2 = __half22float2(wh[2]);
        float2 w3 = __half22float2(wh[3]);
        acc = fmaf(w0.x, ha.x, acc);
        acc = fmaf(w0.y, ha.y, acc);
        acc = fmaf(w1.x, ha.z, acc);
        acc = fmaf(w1.y, ha.w, acc);
        acc = fmaf(w2.x, hb.x, acc);
        acc = fmaf(w2.y, hb.y, acc);
        acc = fmaf(w3.x, hb.z, acc);
        acc = fmaf(w3.y, hb.w, acc);
    }
    const float2* __restrict__ wir = (const float2*)(w_ih + (size_t)row * EMB);
    const float4* __restrict__ o4 = (const float4*)ovec;
    for (int k = lane; k < EMB4; k += 64) {
        float2 wv = wir[k];
        const __half2* wh = (const __half2*)&wv;
        float2 w0 = __half22float2(wh[0]);
        float2 w1 = __half22float2(wh[1]);
        float4 ov = o4[k];
        acc = fmaf(w0.x, ov.x, acc);
        acc = fmaf(w0.y, ov.y, acc);
        acc = fmaf(w1.x, ov.z, acc);
        acc = fmaf(w1.y, ov.w, acc);
    }
    acc = waveReduceSum(acc);
    __shared__ float gl[4];
    if (lane == 0) gl[wave] = acc + b_ih[row] + b_hh[row];
    __syncthreads();
    if (threadIdx.x == 0) {
        float gi = gl[0], gf = gl[1], gg = gl[2], go = gl[3];
        float cp = c[j];
        float cn = sigmoidf_(gf) * cp + sigmoidf_(gi) * tanhf(gg);
        float hn = sigmoidf_(go) * tanhf(cn);
        c[j] = cn;
        h_raw[j] = hn;
    }
}

// ===========================================================================
// fp32 fallback kernels (used only if ws_size can't hold the fp16 copies)
// ===========================================================================
__global__ __launch_bounds__(256) void prime_kernel(
    const float* __restrict__ x, const float* __restrict__ w_ih,
    const float* __restrict__ b_ih, const float* __restrict__ b_hh,
    float* __restrict__ h, float* __restrict__ c)
{
    const int j = blockIdx.x;
    const int wave = threadIdx.x >> 6;
    const int lane = threadIdx.x & 63;
    const int row = j + wave * HID;
    const float4* __restrict__ wr = (const float4*)(w_ih + (size_t)row * EMB);
    const float4* __restrict__ x4 = (const float4*)x;
    float acc = 0.0f;
    for (int k = lane; k < EMB / 4; k += 64) {
        float4 w = wr[k];
        float4 xv = x4[k];
        acc = fmaf(w.x, xv.x, acc);
        acc = fmaf(w.y, xv.y, acc);
        acc = fmaf(w.z, xv.z, acc);
        acc = fmaf(w.w, xv.w, acc);
    }
    acc = waveReduceSum(acc);
    __shared__ float gl[4];
    if (lane == 0) gl[wave] = acc + b_ih[row] + b_hh[row];
    __syncthreads();
    if (threadIdx.x == 0) {
        float gi = gl[0], gg = gl[2], go = gl[3];
        float cn = sigmoidf_(gi) * tanhf(gg);
        float hn = sigmoidf_(go) * tanhf(cn);
        c[j] = cn;
        h[j] = hn;
    }
}

__global__ __launch_bounds__(256) void outvec_kernel(
    const float* __restrict__ h, const float* __restrict__ w_out,
    const float* __restrict__ b_out, float* __restrict__ ovec)
{
    const int i = blockIdx.x;
    const float4* __restrict__ wr = (const float4*)(w_out + (size_t)i * HID);
    const float4* __restrict__ h4 = (const float4*)h;
    float acc = 0.0f;
    for (int k = threadIdx.x; k < HID / 4; k += 256) {
        float4 w = wr[k];
        float4 hv = h4[k];
        acc = fmaf(w.x, hv.x, acc);
        acc = fmaf(w.y, hv.y, acc);
        acc = fmaf(w.z, hv.z, acc);
        acc = fmaf(w.w, hv.w, acc);
    }
    acc = waveReduceSum(acc);
    __shared__ float red[4];
    const int wave = threadIdx.x >> 6;
    const int lane = threadIdx.x & 63;
    if (lane == 0) red[wave] = acc;
    __syncthreads();
    if (threadIdx.x == 0)
        ovec[i] = red[0] + red[1] + red[2] + red[3] + b_out[i];
}

__global__ __launch_bounds__(256) void gates_kernel(
    const float* __restrict__ h, const float* __restrict__ ovec,
    const float* __restrict__ w_hh, const float* __restrict__ w_ih,
    const float* __restrict__ b_ih, const float* __restrict__ b_hh,
    float* __restrict__ c, float* __restrict__ h_raw)
{
    const int j = blockIdx.x;
    const int wave = threadIdx.x >> 6;
    const int lane = threadIdx.x & 63;
    const int row = j + wave * HID;

    const float4* __restrict__ wr = (const float4*)(w_hh + (size_t)row * HID);
    const float4* __restrict__ h4 = (const float4*)h;
    float acc = 0.0f;
    for (int k = lane; k < HID / 4; k += 64) {
        float4 w = wr[k];
        float4 hv = h4[k];
        acc = fmaf(w.x, hv.x, acc);
        acc = fmaf(w.y, hv.y, acc);
        acc = fmaf(w.z, hv.z, acc);
        acc = fmaf(w.w, hv.w, acc);
    }
    const float4* __restrict__ wir = (const float4*)(w_ih + (size_t)row * EMB);
    const float4* __restrict__ o4 = (const float4*)ovec;
    for (int k = lane; k < EMB / 4; k += 64) {
        float4 w = wir[k];
        float4 ov = o4[k];
        acc = fmaf(w.x, ov.x, acc);
        acc = fmaf(w.y, ov.y, acc);
        acc = fmaf(w.z, ov.z, acc);
        acc = fmaf(w.w, ov.w, acc);
    }
    acc = waveReduceSum(acc);
    __shared__ float gl[4];
    if (lane == 0) gl[wave] = acc + b_ih[row] + b_hh[row];
    __syncthreads();
    if (threadIdx.x == 0) {
        float gi = gl[0], gf = gl[1], gg = gl[2], go = gl[3];
        float cp = c[j];
        float cn = sigmoidf_(gf) * cp + sigmoidf_(gi) * tanhf(gg);
        float hn = sigmoidf_(go) * tanhf(cn);
        c[j] = cn;
        h_raw[j] = hn;
    }
}

// ---------------------------------------------------------------------------
// h = softmax(h_raw); also scatter output column t.
// ---------------------------------------------------------------------------
__global__ __launch_bounds__(1024) void softmax_kernel(
    const float* __restrict__ h_raw, float* __restrict__ h,
    float* __restrict__ outp, int t)
{
    __shared__ float red[16];
    __shared__ float bcast;
    const int tid = threadIdx.x;
    const int wave = tid >> 6;
    const int lane = tid & 63;

    float m = -INFINITY;
    for (int k = tid; k < HID; k += 1024) m = fmaxf(m, h_raw[k]);
#pragma unroll
    for (int off = 32; off > 0; off >>= 1) m = fmaxf(m, __shfl_down(m, off, 64));
    if (lane == 0) red[wave] = m;
    __syncthreads();
    if (tid == 0) {
        float mm = red[0];
        for (int i = 1; i < 16; i++) mm = fmaxf(mm, red[i]);
        bcast = mm;
    }
    __syncthreads();
    const float M = bcast;

    float s = 0.0f;
    for (int k = tid; k < HID; k += 1024) s += expf(h_raw[k] - M);
    s = waveReduceSum(s);
    if (lane == 0) red[wave] = s;
    __syncthreads();
    if (tid == 0) {
        float ss = 0.0f;
        for (int i = 0; i < 16; i++) ss += red[i];
        bcast = ss;
    }
    __syncthreads();
    const float invS = 1.0f / bcast;

    for (int k = tid; k < HID; k += 1024) {
        float v = expf(h_raw[k] - M) * invS;
        h[k] = v;
        outp[(size_t)k * NSTEPS + t] = v;
    }
}

extern "C" void kernel_launch(void* const* d_in, const int* in_sizes, int n_in,
                              void* d_out, int out_size, void* d_ws, size_t ws_size,
                              hipStream_t stream)
{
    const float* x     = (const float*)d_in[0];
    const float* w_ih  = (const float*)d_in[1];
    const float* w_hh  = (const float*)d_in[2];
    const float* b_ih  = (const float*)d_in[3];
    const float* b_hh  = (const float*)d_in[4];
    const float* w_out = (const float*)d_in[5];
    const float* b_out = (const float*)d_in[6];
    float* outp = (float*)d_out;

    float* ws = (float*)d_ws;
    // small fp32 state (float offsets; all 16B aligned)
    float* h     = ws;            // 9000
    float* c     = ws + 9216;     // 9000
    float* ovec  = ws + 18432;    // 300
    float* h_raw = ws + 18752;    // 9000

    const size_t WHH_E  = (size_t)4 * HID * HID;  // 324,000,000
    const size_t WIH_E  = (size_t)4 * HID * EMB;  //  10,800,000
    const size_t WOUT_E = (size_t)EMB * HID;      //   2,700,000
    const size_t FP16_BYTES = 131072 + 2 * (WHH_E + WIH_E + WOUT_E);

    if (ws_size >= FP16_BYTES) {
        __half* whh_h  = (__half*)((char*)d_ws + 131072);
        __half* wih_h  = whh_h + WHH_E;
        __half* wout_h = wih_h + WIH_E;

        f32_to_f16_kernel<<<2048, 256, 0, stream>>>(w_hh, whh_h, (int)(WHH_E / 8));
        f32_to_f16_kernel<<<512, 256, 0, stream>>>(w_ih, wih_h, (int)(WIH_E / 8));
        f32_to_f16_kernel<<<256, 256, 0, stream>>>(w_out, wout_h, (int)(WOUT_E / 8));

        prime_kernel_h<<<HID, 256, 0, stream>>>(x, wih_h, b_ih, b_hh, h, c);
        for (int t = 0; t < NSTEPS; ++t) {
            outvec_kernel_h<<<EMB, 256, 0, stream>>>(h, wout_h, b_out, ovec);
            gates_kernel_h<<<HID, 256, 0, stream>>>(h, ovec, whh_h, wih_h, b_ih, b_hh, c, h_raw);
            softmax_kernel<<<1, 1024, 0, stream>>>(h_raw, h, outp, t);
        }
    } else {
        // fp32 fallback (proven path)
        prime_kernel<<<HID, 256, 0, stream>>>(x, w_ih, b_ih, b_hh, h, c);
        for (int t = 0; t < NSTEPS; ++t) {
            outvec_kernel<<<EMB, 256, 0, stream>>>(h, w_out, b_out, ovec);
            gates_kernel<<<HID, 256, 0, stream>>>(h, ovec, w_hh, w_ih, b_ih, b_hh, c, h_raw);
            softmax_kernel<<<1, 1024, 0, stream>>>(h_raw, h, outp, t);
        }
    }
}

// Round 3
// 2767.800 us; speedup vs baseline: 1.8336x; 1.3100x over previous
//
#include <hip/hip_runtime.h>
#include <hip/hip_fp16.h>
#include <math.h>

#define HID 9000
#define EMB 300
#define NSTEPS 20
#define HID8 (HID / 8)     // 1125 eight-half chunks per w_hh/w_out row (fp16)
#define EMB4 (EMB / 4)     // 75 four-half chunks per w_ih row (fp16)
#define ROWB 9216          // fp8 w_hh padded row bytes (576 x 16B chunks)
#define ROWCH 576          // 16B chunks per padded fp8 row
#define F4_PER_ROW 2250    // valid float4 chunks per w_hh fp32 row (9000/4)
#define F4_PAD 2304        // ROWB/4 dwords per padded row
#define FP8_SCALE 16384.0f
#define FP8_INV   6.103515625e-05f

typedef float v2f __attribute__((ext_vector_type(2)));

__device__ __forceinline__ float sigmoidf_(float v) {
    return 1.0f / (1.0f + expf(-v));
}

__device__ __forceinline__ float waveReduceSum(float v) {
#pragma unroll
    for (int off = 32; off > 0; off >>= 1) v += __shfl_down(v, off, 64);
    return v;
}

// ---------------------------------------------------------------------------
// fp32 -> fp16 weight compression (for w_ih, w_out).
// ---------------------------------------------------------------------------
__global__ __launch_bounds__(256) void f32_to_f16_kernel(
    const float* __restrict__ src, __half* __restrict__ dst, int n8)
{
    int i = blockIdx.x * blockDim.x + threadIdx.x;
    const int stride = gridDim.x * blockDim.x;
    const float4* __restrict__ s4 = (const float4*)src;
    float4* __restrict__ d4 = (float4*)dst;
    for (; i < n8; i += stride) {
        float4 a = s4[2 * i];
        float4 b = s4[2 * i + 1];
        float4 o;
        ((__half2*)&o)[0] = __floats2half2_rn(a.x, a.y);
        ((__half2*)&o)[1] = __floats2half2_rn(a.z, a.w);
        ((__half2*)&o)[2] = __floats2half2_rn(b.x, b.y);
        ((__half2*)&o)[3] = __floats2half2_rn(b.z, b.w);
        d4[i] = o;
    }
}

// ---------------------------------------------------------------------------
// Priming step (fp16 w_ih): h,c = lstm_cell(x, 0, 0). Also zeroes h pads.
// ---------------------------------------------------------------------------
__global__ __launch_bounds__(256) void prime_kernel_h(
    const float* __restrict__ x, const __half* __restrict__ w_ih,
    const float* __restrict__ b_ih, const float* __restrict__ b_hh,
    float* __restrict__ h, float* __restrict__ c)
{
    const int j = blockIdx.x;
    const int wave = threadIdx.x >> 6;
    const int lane = threadIdx.x & 63;
    const int row = j + wave * HID;
    const float2* __restrict__ wr = (const float2*)(w_ih + (size_t)row * EMB);
    const float4* __restrict__ x4 = (const float4*)x;
    float acc = 0.0f;
    for (int k = lane; k < EMB4; k += 64) {
        float2 wv = wr[k];
        const __half2* wh = (const __half2*)&wv;
        float2 w0 = __half22float2(wh[0]);
        float2 w1 = __half22float2(wh[1]);
        float4 xv = x4[k];
        acc = fmaf(w0.x, xv.x, acc);
        acc = fmaf(w0.y, xv.y, acc);
        acc = fmaf(w1.x, xv.z, acc);
        acc = fmaf(w1.y, xv.w, acc);
    }
    acc = waveReduceSum(acc);
    __shared__ float gl[4];
    if (lane == 0) gl[wave] = acc + b_ih[row] + b_hh[row];
    __syncthreads();
    if (threadIdx.x == 0) {
        float gi = gl[0], gg = gl[2], go = gl[3];
        float cn = sigmoidf_(gi) * tanhf(gg);
        float hn = sigmoidf_(go) * tanhf(cn);
        c[j] = cn;
        h[j] = hn;
    }
    if (blockIdx.x == 0 && threadIdx.x < 216) h[HID + threadIdx.x] = 0.0f;
}

// ---------------------------------------------------------------------------
// out = h @ w_out.T + b_out  (fp16 w_out)
// ---------------------------------------------------------------------------
__global__ __launch_bounds__(256) void outvec_kernel_h(
    const float* __restrict__ h, const __half* __restrict__ w_out,
    const float* __restrict__ b_out, float* __restrict__ ovec)
{
    const int i = blockIdx.x;
    const float4* __restrict__ wr = (const float4*)(w_out + (size_t)i * HID);
    const float4* __restrict__ h4 = (const float4*)h;
    float acc = 0.0f;
    for (int k = threadIdx.x; k < HID8; k += 256) {
        float4 wv = wr[k];
        const __half2* wh = (const __half2*)&wv;
        float4 ha = h4[2 * k];
        float4 hb = h4[2 * k + 1];
        float2 w0 = __half22float2(wh[0]);
        float2 w1 = __half22float2(wh[1]);
        float2 w2 = __half22float2(wh[2]);
        float2 w3 = __half22float2(wh[3]);
        acc = fmaf(w0.x, ha.x, acc);
        acc = fmaf(w0.y, ha.y, acc);
        acc = fmaf(w1.x, ha.z, acc);
        acc = fmaf(w1.y, ha.w, acc);
        acc = fmaf(w2.x, hb.x, acc);
        acc = fmaf(w2.y, hb.y, acc);
        acc = fmaf(w3.x, hb.z, acc);
        acc = fmaf(w3.y, hb.w, acc);
    }
    acc = waveReduceSum(acc);
    __shared__ float red[4];
    const int wave = threadIdx.x >> 6;
    const int lane = threadIdx.x & 63;
    if (lane == 0) red[wave] = acc;
    __syncthreads();
    if (threadIdx.x == 0)
        ovec[i] = red[0] + red[1] + red[2] + red[3] + b_out[i];
}

// ---------------------------------------------------------------------------
// Shared cell-update epilogue (acc already holds full gate preactivation
// minus biases, per wave in gl[]).
// ---------------------------------------------------------------------------
__device__ __forceinline__ void cell_epilogue(
    float acc, int j, int row, int wave, int lane,
    const float* b_ih, const float* b_hh, float* c, float* h_raw)
{
    acc = waveReduceSum(acc);
    __shared__ float gl[4];
    if (lane == 0) gl[wave] = acc + b_ih[row] + b_hh[row];
    __syncthreads();
    if (wave == 0 && lane == 0) {
        float gi = gl[0], gf = gl[1], gg = gl[2], go = gl[3];
        float cp = c[j];
        float cn = sigmoidf_(gf) * cp + sigmoidf_(gi) * tanhf(gg);
        float hn = sigmoidf_(go) * tanhf(cn);
        c[j] = cn;
        h_raw[j] = hn;
    }
}

// ---------------------------------------------------------------------------
// Fused t=0: streams w_hh in fp32 (exact GEMV) while writing the fp8 copy
// (padded rows, scale 2^14). One block per hidden unit; wave owns a gate row.
// ---------------------------------------------------------------------------
__global__ __launch_bounds__(256) void convgates_kernel(
    const float* __restrict__ h, const float* __restrict__ ovec,
    const float* __restrict__ w_hh, unsigned int* __restrict__ whh8,
    const __half* __restrict__ w_ih,
    const float* __restrict__ b_ih, const float* __restrict__ b_hh,
    float* __restrict__ c, float* __restrict__ h_raw)
{
    const int j = blockIdx.x;
    const int wave = threadIdx.x >> 6;
    const int lane = threadIdx.x & 63;
    const int row = j + wave * HID;

    const float4* __restrict__ w4 = (const float4*)(w_hh + (size_t)row * HID);
    unsigned int* __restrict__ dst = whh8 + (size_t)row * (ROWB / 4);
    const float4* __restrict__ h4 = (const float4*)h;
    float acc = 0.0f;
    for (int it = 0; it < 36; ++it) {
        const int ci = it * 64 + lane;        // float4 index within row
        unsigned int pack = 0u;
        if (ci < F4_PER_ROW) {
            float4 wv = w4[ci];
            float4 hv = h4[ci];
            acc = fmaf(wv.x, hv.x, acc);
            acc = fmaf(wv.y, hv.y, acc);
            acc = fmaf(wv.z, hv.z, acc);
            acc = fmaf(wv.w, hv.w, acc);
            pack = (unsigned int)__builtin_amdgcn_cvt_pk_fp8_f32(
                       wv.x * FP8_SCALE, wv.y * FP8_SCALE, 0, false);
            pack = (unsigned int)__builtin_amdgcn_cvt_pk_fp8_f32(
                       wv.z * FP8_SCALE, wv.w * FP8_SCALE, (int)pack, true);
        }
        if (ci < F4_PAD) dst[ci] = pack;      // pad dwords get 0
    }
    // w_ih (fp16) * ovec part
    const float2* __restrict__ wir = (const float2*)(w_ih + (size_t)row * EMB);
    const float4* __restrict__ o4 = (const float4*)ovec;
    for (int k = lane; k < EMB4; k += 64) {
        float2 wv = wir[k];
        const __half2* wh = (const __half2*)&wv;
        float2 w0 = __half22float2(wh[0]);
        float2 w1 = __half22float2(wh[1]);
        float4 ov = o4[k];
        acc = fmaf(w0.x, ov.x, acc);
        acc = fmaf(w0.y, ov.y, acc);
        acc = fmaf(w1.x, ov.z, acc);
        acc = fmaf(w1.y, ov.w, acc);
    }
    cell_epilogue(acc, j, row, wave, lane, b_ih, b_hh, c, h_raw);
}

// ---------------------------------------------------------------------------
// Steady-state gates (t>=1): fp8 w_hh (padded rows), fp16 w_ih.
// h must be padded to 9216 floats with zeros in [9000,9216).
// ---------------------------------------------------------------------------
__global__ __launch_bounds__(256) void gates_kernel_8(
    const float* __restrict__ h, const float* __restrict__ ovec,
    const unsigned int* __restrict__ whh8, const __half* __restrict__ w_ih,
    const float* __restrict__ b_ih, const float* __restrict__ b_hh,
    float* __restrict__ c, float* __restrict__ h_raw)
{
    const int j = blockIdx.x;
    const int wave = threadIdx.x >> 6;
    const int lane = threadIdx.x & 63;
    const int row = j + wave * HID;

    const uint4* __restrict__ wp = (const uint4*)(whh8 + (size_t)row * (ROWB / 4));
    const float4* __restrict__ h4 = (const float4*)h;
    float acc = 0.0f;
#pragma unroll 3
    for (int it = 0; it < 9; ++it) {
        const int ci = it * 64 + lane;        // 16B chunk index, 0..575
        uint4 wb = wp[ci];
        float4 ha = h4[4 * ci + 0];
        float4 hb = h4[4 * ci + 1];
        float4 hc = h4[4 * ci + 2];
        float4 hd = h4[4 * ci + 3];
        v2f p;
        p = __builtin_amdgcn_cvt_pk_f32_fp8((int)wb.x, false);
        acc = fmaf(p.x, ha.x, acc); acc = fmaf(p.y, ha.y, acc);
        p = __builtin_amdgcn_cvt_pk_f32_fp8((int)wb.x, true);
        acc = fmaf(p.x, ha.z, acc); acc = fmaf(p.y, ha.w, acc);
        p = __builtin_amdgcn_cvt_pk_f32_fp8((int)wb.y, false);
        acc = fmaf(p.x, hb.x, acc); acc = fmaf(p.y, hb.y, acc);
        p = __builtin_amdgcn_cvt_pk_f32_fp8((int)wb.y, true);
        acc = fmaf(p.x, hb.z, acc); acc = fmaf(p.y, hb.w, acc);
        p = __builtin_amdgcn_cvt_pk_f32_fp8((int)wb.z, false);
        acc = fmaf(p.x, hc.x, acc); acc = fmaf(p.y, hc.y, acc);
        p = __builtin_amdgcn_cvt_pk_f32_fp8((int)wb.z, true);
        acc = fmaf(p.x, hc.z, acc); acc = fmaf(p.y, hc.w, acc);
        p = __builtin_amdgcn_cvt_pk_f32_fp8((int)wb.w, false);
        acc = fmaf(p.x, hd.x, acc); acc = fmaf(p.y, hd.y, acc);
        p = __builtin_amdgcn_cvt_pk_f32_fp8((int)wb.w, true);
        acc = fmaf(p.x, hd.z, acc); acc = fmaf(p.y, hd.w, acc);
    }
    acc *= FP8_INV;   // undo the 2^14 weight scale

    const float2* __restrict__ wir = (const float2*)(w_ih + (size_t)row * EMB);
    const float4* __restrict__ o4 = (const float4*)ovec;
    for (int k = lane; k < EMB4; k += 64) {
        float2 wv = wir[k];
        const __half2* wh = (const __half2*)&wv;
        float2 w0 = __half22float2(wh[0]);
        float2 w1 = __half22float2(wh[1]);
        float4 ov = o4[k];
        acc = fmaf(w0.x, ov.x, acc);
        acc = fmaf(w0.y, ov.y, acc);
        acc = fmaf(w1.x, ov.z, acc);
        acc = fmaf(w1.y, ov.w, acc);
    }
    cell_epilogue(acc, j, row, wave, lane, b_ih, b_hh, c, h_raw);
}

// ===========================================================================
// fp16 / fp32 fallback gates + prime + outvec (proven paths)
// ===========================================================================
__global__ __launch_bounds__(256) void gates_kernel_h(
    const float* __restrict__ h, const float* __restrict__ ovec,
    const __half* __restrict__ w_hh, const __half* __restrict__ w_ih,
    const float* __restrict__ b_ih, const float* __restrict__ b_hh,
    float* __restrict__ c, float* __restrict__ h_raw)
{
    const int j = blockIdx.x;
    const int wave = threadIdx.x >> 6;
    const int lane = threadIdx.x & 63;
    const int row = j + wave * HID;

    const float4* __restrict__ wr = (const float4*)(w_hh + (size_t)row * HID);
    const float4* __restrict__ h4 = (const float4*)h;
    float acc = 0.0f;
    for (int k = lane; k < HID8; k += 64) {
        float4 wv = wr[k];
        const __half2* wh = (const __half2*)&wv;
        float4 ha = h4[2 * k];
        float4 hb = h4[2 * k + 1];
        float2 w0 = __half22float2(wh[0]);
        float2 w1 = __half22float2(wh[1]);
        float2 w2 = __half22float2(wh[2]);
        float2 w3 = __half22float2(wh[3]);
        acc = fmaf(w0.x, ha.x, acc);
        acc = fmaf(w0.y, ha.y, acc);
        acc = fmaf(w1.x, ha.z, acc);
        acc = fmaf(w1.y, ha.w, acc);
        acc = fmaf(w2.x, hb.x, acc);
        acc = fmaf(w2.y, hb.y, acc);
        acc = fmaf(w3.x, hb.z, acc);
        acc = fmaf(w3.y, hb.w, acc);
    }
    const float2* __restrict__ wir = (const float2*)(w_ih + (size_t)row * EMB);
    const float4* __restrict__ o4 = (const float4*)ovec;
    for (int k = lane; k < EMB4; k += 64) {
        float2 wv = wir[k];
        const __half2* wh = (const __half2*)&wv;
        float2 w0 = __half22float2(wh[0]);
        float2 w1 = __half22float2(wh[1]);
        float4 ov = o4[k];
        acc = fmaf(w0.x, ov.x, acc);
        acc = fmaf(w0.y, ov.y, acc);
        acc = fmaf(w1.x, ov.z, acc);
        acc = fmaf(w1.y, ov.w, acc);
    }
    cell_epilogue(acc, j, row, wave, lane, b_ih, b_hh, c, h_raw);
}

__global__ __launch_bounds__(256) void prime_kernel(
    const float* __restrict__ x, const float* __restrict__ w_ih,
    const float* __restrict__ b_ih, const float* __restrict__ b_hh,
    float* __restrict__ h, float* __restrict__ c)
{
    const int j = blockIdx.x;
    const int wave = threadIdx.x >> 6;
    const int lane = threadIdx.x & 63;
    const int row = j + wave * HID;
    const float4* __restrict__ wr = (const float4*)(w_ih + (size_t)row * EMB);
    const float4* __restrict__ x4 = (const float4*)x;
    float acc = 0.0f;
    for (int k = lane; k < EMB / 4; k += 64) {
        float4 w = wr[k];
        float4 xv = x4[k];
        acc = fmaf(w.x, xv.x, acc);
        acc = fmaf(w.y, xv.y, acc);
        acc = fmaf(w.z, xv.z, acc);
        acc = fmaf(w.w, xv.w, acc);
    }
    acc = waveReduceSum(acc);
    __shared__ float gl[4];
    if (lane == 0) gl[wave] = acc + b_ih[row] + b_hh[row];
    __syncthreads();
    if (threadIdx.x == 0) {
        float gi = gl[0], gg = gl[2], go = gl[3];
        float cn = sigmoidf_(gi) * tanhf(gg);
        float hn = sigmoidf_(go) * tanhf(cn);
        c[j] = cn;
        h[j] = hn;
    }
    if (blockIdx.x == 0 && threadIdx.x < 216) h[HID + threadIdx.x] = 0.0f;
}

__global__ __launch_bounds__(256) void outvec_kernel(
    const float* __restrict__ h, const float* __restrict__ w_out,
    const float* __restrict__ b_out, float* __restrict__ ovec)
{
    const int i = blockIdx.x;
    const float4* __restrict__ wr = (const float4*)(w_out + (size_t)i * HID);
    const float4* __restrict__ h4 = (const float4*)h;
    float acc = 0.0f;
    for (int k = threadIdx.x; k < HID / 4; k += 256) {
        float4 w = wr[k];
        float4 hv = h4[k];
        acc = fmaf(w.x, hv.x, acc);
        acc = fmaf(w.y, hv.y, acc);
        acc = fmaf(w.z, hv.z, acc);
        acc = fmaf(w.w, hv.w, acc);
    }
    acc = waveReduceSum(acc);
    __shared__ float red[4];
    const int wave = threadIdx.x >> 6;
    const int lane = threadIdx.x & 63;
    if (lane == 0) red[wave] = acc;
    __syncthreads();
    if (threadIdx.x == 0)
        ovec[i] = red[0] + red[1] + red[2] + red[3] + b_out[i];
}

__global__ __launch_bounds__(256) void gates_kernel(
    const float* __restrict__ h, const float* __restrict__ ovec,
    const float* __restrict__ w_hh, const float* __restrict__ w_ih,
    const float* __restrict__ b_ih, const float* __restrict__ b_hh,
    float* __restrict__ c, float* __restrict__ h_raw)
{
    const int j = blockIdx.x;
    const int wave = threadIdx.x >> 6;
    const int lane = threadIdx.x & 63;
    const int row = j + wave * HID;

    const float4* __restrict__ wr = (const float4*)(w_hh + (size_t)row * HID);
    const float4* __restrict__ h4 = (const float4*)h;
    float acc = 0.0f;
    for (int k = lane; k < HID / 4; k += 64) {
        float4 w = wr[k];
        float4 hv = h4[k];
        acc = fmaf(w.x, hv.x, acc);
        acc = fmaf(w.y, hv.y, acc);
        acc = fmaf(w.z, hv.z, acc);
        acc = fmaf(w.w, hv.w, acc);
    }
    const float4* __restrict__ wir = (const float4*)(w_ih + (size_t)row * EMB);
    const float4* __restrict__ o4 = (const float4*)ovec;
    for (int k = lane; k < EMB / 4; k += 64) {
        float4 w = wir[k];
        float4 ov = o4[k];
        acc = fmaf(w.x, ov.x, acc);
        acc = fmaf(w.y, ov.y, acc);
        acc = fmaf(w.z, ov.z, acc);
        acc = fmaf(w.w, ov.w, acc);
    }
    cell_epilogue(acc, j, row, wave, lane, b_ih, b_hh, c, h_raw);
}

// ---------------------------------------------------------------------------
// h = softmax(h_raw); scatter output column t; zero h pads [9000,9216).
// ---------------------------------------------------------------------------
__global__ __launch_bounds__(1024) void softmax_kernel(
    const float* __restrict__ h_raw, float* __restrict__ h,
    float* __restrict__ outp, int t)
{
    __shared__ float red[16];
    __shared__ float bcast;
    const int tid = threadIdx.x;
    const int wave = tid >> 6;
    const int lane = tid & 63;

    float m = -INFINITY;
    for (int k = tid; k < HID; k += 1024) m = fmaxf(m, h_raw[k]);
#pragma unroll
    for (int off = 32; off > 0; off >>= 1) m = fmaxf(m, __shfl_down(m, off, 64));
    if (lane == 0) red[wave] = m;
    __syncthreads();
    if (tid == 0) {
        float mm = red[0];
        for (int i = 1; i < 16; i++) mm = fmaxf(mm, red[i]);
        bcast = mm;
    }
    __syncthreads();
    const float M = bcast;

    float s = 0.0f;
    for (int k = tid; k < HID; k += 1024) s += expf(h_raw[k] - M);
    s = waveReduceSum(s);
    if (lane == 0) red[wave] = s;
    __syncthreads();
    if (tid == 0) {
        float ss = 0.0f;
        for (int i = 0; i < 16; i++) ss += red[i];
        bcast = ss;
    }
    __syncthreads();
    const float invS = 1.0f / bcast;

    for (int k = tid; k < HID; k += 1024) {
        float v = expf(h_raw[k] - M) * invS;
        h[k] = v;
        outp[(size_t)k * NSTEPS + t] = v;
    }
    if (tid < 216) h[HID + tid] = 0.0f;   // keep fp8-path pads zero
}

extern "C" void kernel_launch(void* const* d_in, const int* in_sizes, int n_in,
                              void* d_out, int out_size, void* d_ws, size_t ws_size,
                              hipStream_t stream)
{
    const float* x     = (const float*)d_in[0];
    const float* w_ih  = (const float*)d_in[1];
    const float* w_hh  = (const float*)d_in[2];
    const float* b_ih  = (const float*)d_in[3];
    const float* b_hh  = (const float*)d_in[4];
    const float* w_out = (const float*)d_in[5];
    const float* b_out = (const float*)d_in[6];
    float* outp = (float*)d_out;

    float* ws = (float*)d_ws;
    // small fp32 state (h padded to 9216 floats for the fp8 path)
    float* h     = ws;            // 9216
    float* c     = ws + 9216;     // 9000 (+pad)
    float* ovec  = ws + 18432;    // 300 (+pad)
    float* h_raw = ws + 18752;    // 9000

    const size_t WHH_E  = (size_t)4 * HID * HID;  // 324,000,000
    const size_t WIH_E  = (size_t)4 * HID * EMB;  //  10,800,000
    const size_t WOUT_E = (size_t)EMB * HID;      //   2,700,000
    const size_t WHH8_BYTES = (size_t)4 * HID * ROWB;  // 331,776,000
    const size_t FP8_BYTES  = 131072 + WHH8_BYTES + 2 * (WIH_E + WOUT_E);
    const size_t FP16_BYTES = 131072 + 2 * (WHH_E + WIH_E + WOUT_E);

    if (ws_size >= FP8_BYTES) {
        unsigned int* whh8 = (unsigned int*)((char*)d_ws + 131072);
        __half* wih_h  = (__half*)((char*)d_ws + 131072 + WHH8_BYTES);
        __half* wout_h = wih_h + WIH_E;

        f32_to_f16_kernel<<<512, 256, 0, stream>>>(w_ih, wih_h, (int)(WIH_E / 8));
        f32_to_f16_kernel<<<256, 256, 0, stream>>>(w_out, wout_h, (int)(WOUT_E / 8));

        prime_kernel_h<<<HID, 256, 0, stream>>>(x, wih_h, b_ih, b_hh, h, c);
        // t = 0: fused fp32 GEMV + fp8 conversion of w_hh
        outvec_kernel_h<<<EMB, 256, 0, stream>>>(h, wout_h, b_out, ovec);
        convgates_kernel<<<HID, 256, 0, stream>>>(h, ovec, w_hh, whh8, wih_h,
                                                  b_ih, b_hh, c, h_raw);
        softmax_kernel<<<1, 1024, 0, stream>>>(h_raw, h, outp, 0);
        for (int t = 1; t < NSTEPS; ++t) {
            outvec_kernel_h<<<EMB, 256, 0, stream>>>(h, wout_h, b_out, ovec);
            gates_kernel_8<<<HID, 256, 0, stream>>>(h, ovec, whh8, wih_h,
                                                    b_ih, b_hh, c, h_raw);
            softmax_kernel<<<1, 1024, 0, stream>>>(h_raw, h, outp, t);
        }
    } else if (ws_size >= FP16_BYTES) {
        __half* whh_h  = (__half*)((char*)d_ws + 131072);
        __half* wih_h  = whh_h + WHH_E;
        __half* wout_h = wih_h + WIH_E;

        f32_to_f16_kernel<<<2048, 256, 0, stream>>>(w_hh, whh_h, (int)(WHH_E / 8));
        f32_to_f16_kernel<<<512, 256, 0, stream>>>(w_ih, wih_h, (int)(WIH_E / 8));
        f32_to_f16_kernel<<<256, 256, 0, stream>>>(w_out, wout_h, (int)(WOUT_E / 8));

        prime_kernel_h<<<HID, 256, 0, stream>>>(x, wih_h, b_ih, b_hh, h, c);
        for (int t = 0; t < NSTEPS; ++t) {
            outvec_kernel_h<<<EMB, 256, 0, stream>>>(h, wout_h, b_out, ovec);
            gates_kernel_h<<<HID, 256, 0, stream>>>(h, ovec, whh_h, wih_h,
                                                    b_ih, b_hh, c, h_raw);
            softmax_kernel<<<1, 1024, 0, stream>>>(h_raw, h, outp, t);
        }
    } else {
        prime_kernel<<<HID, 256, 0, stream>>>(x, w_ih, b_ih, b_hh, h, c);
        for (int t = 0; t < NSTEPS; ++t) {
            outvec_kernel<<<EMB, 256, 0, stream>>>(h, w_out, b_out, ovec);
            gates_kernel<<<HID, 256, 0, stream>>>(h, ovec, w_hh, w_ih, b_ih, b_hh, c, h_raw);
            softmax_kernel<<<1, 1024, 0, stream>>>(h_raw, h, outp, t);
        }
    }
}